// Round 4
// baseline (3382.247 us; speedup 1.0000x reference)
//
#include <hip/hip_runtime.h>
#include <hip/hip_bf16.h>
#include <math.h>

#define N_ROWS 16384      // 8*2048
#define DM 1024
#define HALF 512
#define NC 4096
#define NS 1024
#define DELTA 2e-3f       // unnormalized-sims gap threshold for f64 rescore

// f32-element offsets into d_out (chunks in reference return order)
#define COMB_N   16777216
#define IDXC_OFF 16777217
#define IDXS_OFF 16793601
#define DIS_OFF  16809985

__device__ __forceinline__ int clampi(int v, int hi){ return v < 0 ? 0 : (v > hi ? hi : v); }

__device__ __forceinline__ float blockSum256(float v, float* red){
  #pragma unroll
  for (int m=1;m<64;m<<=1) v += __shfl_xor(v, m, 64);
  __syncthreads();
  if ((threadIdx.x & 63) == 0) red[threadIdx.x>>6] = v;
  __syncthreads();
  return (red[0]+red[1])+(red[2]+red[3]);
}
__device__ __forceinline__ double blockSumD(double v, double* red){
  #pragma unroll
  for (int m=1;m<64;m<<=1) v += __shfl_xor(v, m, 64);
  __syncthreads();
  if ((threadIdx.x & 63) == 0) red[threadIdx.x>>6] = v;
  __syncthreads();
  return (red[0]+red[1])+(red[2]+red[3]);
}

// ---------------- init ----------------
__global__ void k_init(float* accum, int* count){
  if (threadIdx.x < 8) accum[threadIdx.x] = 0.f;
  if (threadIdx.x == 0) *count = 0;
}

// ---------------- normalize codebooks (f32) ----------------
__global__ __launch_bounds__(64) void k_norm_cb(const float* __restrict__ ccb, const float* __restrict__ scb,
                                                float* __restrict__ cbn_c, float* __restrict__ cbn_s){
  int b = blockIdx.x, t = threadIdx.x;
  const float* src; float* dst;
  if (b < NC){ src = ccb + (size_t)b*HALF; dst = cbn_c + (size_t)b*HALF; }
  else       { src = scb + (size_t)(b-NC)*HALF; dst = cbn_s + (size_t)(b-NC)*HALF; }
  float4 a = ((const float4*)src)[t];
  float4 c = ((const float4*)src)[t+64];
  float s = a.x*a.x+a.y*a.y+a.z*a.z+a.w*a.w + c.x*c.x+c.y*c.y+c.z*c.z+c.w*c.w;
  #pragma unroll
  for (int m=1;m<64;m<<=1) s += __shfl_xor(s, m, 64);
  float inv = 1.0f / fmaxf(sqrtf(s), 1e-12f);
  a.x*=inv; a.y*=inv; a.z*=inv; a.w*=inv;
  c.x*=inv; c.y*=inv; c.z*=inv; c.w*=inv;
  ((float4*)dst)[t] = a; ((float4*)dst)[t+64] = c;
}

// ---------------- per-row mean / rstd of x ----------------
__global__ __launch_bounds__(256) void k_row_stats(const float* __restrict__ x, float* __restrict__ mu, float* __restrict__ rstd){
  __shared__ float red[4];
  int r = blockIdx.x, t = threadIdx.x;
  float4 v = ((const float4*)(x + (size_t)r*DM))[t];
  float mean = blockSum256((v.x+v.y)+(v.z+v.w), red) * (1.0f/1024.0f);
  float dx=v.x-mean, dy=v.y-mean, dz=v.z-mean, dw=v.w-mean;
  float var = blockSum256((dx*dx+dy*dy)+(dz*dz+dw*dw), red) * (1.0f/1024.0f);
  if (t == 0){ mu[r] = mean; rstd[r] = 1.0f/sqrtf(var + 1e-5f); }
}

// ---------------- bias2[j] = b[j] + sum_k b_ln[k]*w[k][j] ----------------
__global__ __launch_bounds__(256) void k_bias2(const float* __restrict__ w_c, const float* __restrict__ w_s,
                                               const float* __restrict__ bc_ln, const float* __restrict__ bs_ln,
                                               const float* __restrict__ b_c, const float* __restrict__ b_s,
                                               float* __restrict__ bias2){
  int j = blockIdx.x*256 + threadIdx.x;
  float acc = 0.f;
  if (j < HALF){
    for (int k=0;k<DM;k++) acc += bc_ln[k]*w_c[(size_t)k*HALF + j];
    acc += b_c[j];
  } else {
    int jj = j - HALF;
    for (int k=0;k<DM;k++) acc += bs_ln[k]*w_s[(size_t)k*HALF + jj];
    acc += b_s[jj];
  }
  bias2[j] = acc;
}

// ---------------- features GEMM: feat = tanh(z @ (g.w) + bias2), z=(x-mu)*rstd ----------------
__global__ __launch_bounds__(256) void k_gemm_feat(const float* __restrict__ x,
    const float* __restrict__ mu, const float* __restrict__ rstd,
    const float* __restrict__ w_c, const float* __restrict__ w_s,
    const float* __restrict__ gc, const float* __restrict__ gs,
    const float* __restrict__ bias2, float* __restrict__ feat){
  __shared__ __align__(16) float As[16][132];
  __shared__ __align__(16) float Bs[16][128];
  int row0 = blockIdx.x*128, col0 = blockIdx.y*128;
  const float* w = (col0 < HALF) ? w_c : w_s;
  const float* g = (col0 < HALF) ? gc  : gs;
  int wcol0 = (col0 < HALF) ? col0 : (col0 - HALF);
  int t = threadIdx.x;
  int tr = t & 15, tc = t >> 4;
  float acc[8][8];
  #pragma unroll
  for (int i=0;i<8;i++){
    #pragma unroll
    for (int j=0;j<8;j++) acc[i][j]=0.f;
  }
  for (int k0=0;k0<DM;k0+=16){
    #pragma unroll
    for (int i=0;i<2;i++){
      int s = t + i*256; int kq = s&3, rr = s>>2;
      int gr = row0 + rr;
      float4 v = *(const float4*)(x + (size_t)gr*DM + k0 + kq*4);
      float m = mu[gr], rs = rstd[gr];
      As[kq*4+0][rr]=(v.x-m)*rs; As[kq*4+1][rr]=(v.y-m)*rs;
      As[kq*4+2][rr]=(v.z-m)*rs; As[kq*4+3][rr]=(v.w-m)*rs;
    }
    #pragma unroll
    for (int i=0;i<2;i++){
      int s = t + i*256; int jq = s&31, k = s>>5;
      float gv = g[k0+k];
      float4 v = *(const float4*)(w + (size_t)(k0+k)*HALF + wcol0 + jq*4);
      Bs[k][jq*4+0] = gv*v.x; Bs[k][jq*4+1] = gv*v.y;
      Bs[k][jq*4+2] = gv*v.z; Bs[k][jq*4+3] = gv*v.w;
    }
    __syncthreads();
    #pragma unroll
    for (int k=0;k<16;k++){
      float a[8], bb[8];
      *(float4*)&a[0] = *(const float4*)&As[k][tr*8];
      *(float4*)&a[4] = *(const float4*)&As[k][tr*8+4];
      *(float4*)&bb[0] = *(const float4*)&Bs[k][tc*8];
      *(float4*)&bb[4] = *(const float4*)&Bs[k][tc*8+4];
      #pragma unroll
      for (int i=0;i<8;i++)
        #pragma unroll
        for (int j=0;j<8;j++) acc[i][j] += a[i]*bb[j];
    }
    __syncthreads();
  }
  int gc0 = col0 + tc*8;
  #pragma unroll
  for (int i=0;i<8;i++){
    int gr = row0 + tr*8 + i;
    float o[8];
    #pragma unroll
    for (int j=0;j<8;j++) o[j] = tanhf(acc[i][j] + bias2[gc0+j]);
    *(float4*)(feat + (size_t)gr*DM + gc0)     = *(float4*)&o[0];
    *(float4*)(feat + (size_t)gr*DM + gc0 + 4) = *(float4*)&o[4];
  }
}

// ---------------- sims + per-row running top2 (argmax phase 1, f32, scale-invariant) ----------------
__global__ __launch_bounds__(256) void k_sims(const float* __restrict__ feat, int featoff,
    const float* __restrict__ cbn, int ncodes,
    float* __restrict__ pv1, int* __restrict__ pi1, float* __restrict__ pv2){
  __shared__ __align__(16) float As[16][68];
  __shared__ __align__(16) float Bs[16][132];
  int row0 = blockIdx.x*64;
  int cchunk = ncodes >> 2;
  int c0base = blockIdx.y * cchunk;
  int t = threadIdx.x;
  int cg = t & 31, rg = t >> 5;
  float rv1[8], rv2[8]; int ri1[8];
  #pragma unroll
  for (int i=0;i<8;i++){ rv1[i]=-1e30f; rv2[i]=-1e30f; ri1[i]=0; }
  for (int c0 = c0base; c0 < c0base + cchunk; c0 += 128){
    float acc[8][4];
    #pragma unroll
    for (int i=0;i<8;i++){
      #pragma unroll
      for (int j=0;j<4;j++) acc[i][j]=0.f;
    }
    for (int k0=0;k0<HALF;k0+=16){
      { int kq = t&3, rr = t>>2;
        float4 v = *(const float4*)(feat + (size_t)(row0+rr)*DM + featoff + k0 + kq*4);
        As[kq*4+0][rr]=v.x; As[kq*4+1][rr]=v.y; As[kq*4+2][rr]=v.z; As[kq*4+3][rr]=v.w; }
      #pragma unroll
      for (int i=0;i<2;i++){
        int s = t + i*256; int kq = s&3, c = s>>2;
        float4 v = *(const float4*)(cbn + (size_t)(c0+c)*HALF + k0 + kq*4);
        Bs[kq*4+0][c]=v.x; Bs[kq*4+1][c]=v.y; Bs[kq*4+2][c]=v.z; Bs[kq*4+3][c]=v.w; }
      __syncthreads();
      #pragma unroll
      for (int k=0;k<16;k++){
        float a0[4], a1[4], bb[4];
        *(float4*)a0 = *(const float4*)&As[k][rg*8];
        *(float4*)a1 = *(const float4*)&As[k][rg*8+4];
        *(float4*)bb = *(const float4*)&Bs[k][cg*4];
        #pragma unroll
        for (int i=0;i<4;i++)
          #pragma unroll
          for (int j=0;j<4;j++){ acc[i][j] += a0[i]*bb[j]; acc[i+4][j] += a1[i]*bb[j]; }
      }
      __syncthreads();
    }
    #pragma unroll
    for (int i=0;i<8;i++){
      float v1 = acc[i][0]; int i1 = c0 + cg*4; float v2 = -1e30f;
      #pragma unroll
      for (int j=1;j<4;j++){
        float v = acc[i][j];
        if (v > v1){ v2 = v1; v1 = v; i1 = c0 + cg*4 + j; }
        else v2 = fmaxf(v2, v);
      }
      #pragma unroll
      for (int m=1;m<32;m<<=1){
        float o1 = __shfl_xor(v1, m, 64);
        int   oi = __shfl_xor(i1, m, 64);
        float o2 = __shfl_xor(v2, m, 64);
        if (o1 > v1){ v2 = fmaxf(v1, o2); v1 = o1; i1 = oi; }
        else { if (o1 == v1 && oi < i1) i1 = oi; v2 = fmaxf(v2, o1); }
      }
      if (v1 > rv1[i]){ rv2[i] = fmaxf(rv1[i], v2); rv1[i] = v1; ri1[i] = i1; }
      else { if (v1 == rv1[i] && i1 < ri1[i]) ri1[i] = i1; rv2[i] = fmaxf(rv2[i], v1); }
    }
  }
  if (cg == 0){
    int sbase = blockIdx.y * N_ROWS;
    #pragma unroll
    for (int i=0;i<8;i++){
      int r = row0 + rg*8 + i;
      pv1[sbase + r] = rv1[i];
      pi1[sbase + r] = ri1[i];
      pv2[sbase + r] = rv2[i];
    }
  }
}

// ---------------- merge 4-way splits, flag close calls ----------------
__global__ __launch_bounds__(256) void k_argmax_merge(
    const float* __restrict__ pcv1, const int* __restrict__ pci1, const float* __restrict__ pcv2,
    const float* __restrict__ psv1, const int* __restrict__ psi1, const float* __restrict__ psv2,
    int* __restrict__ idx_c, int* __restrict__ idx_s,
    int* __restrict__ count, int* __restrict__ list){
  int r = blockIdx.x*256 + threadIdx.x;
  {
    float v1=-1e30f, v2=-1e30f; int i1=0;
    #pragma unroll
    for (int sp=0; sp<4; sp++){
      float a1 = pcv1[sp*N_ROWS + r]; int ai = pci1[sp*N_ROWS + r]; float a2 = pcv2[sp*N_ROWS + r];
      if (a1 > v1){ v2 = fmaxf(v1, a2); v1 = a1; i1 = ai; }
      else { if (a1 == v1 && ai < i1) i1 = ai; v2 = fmaxf(v2, a1); }
    }
    idx_c[r] = i1;
    if (v1 - v2 < DELTA){ int p = atomicAdd(count, 1); if (p < 2*N_ROWS) list[p] = r; }
  }
  {
    float v1=-1e30f, v2=-1e30f; int i1=0;
    #pragma unroll
    for (int sp=0; sp<4; sp++){
      float a1 = psv1[sp*N_ROWS + r]; int ai = psi1[sp*N_ROWS + r]; float a2 = psv2[sp*N_ROWS + r];
      if (a1 > v1){ v2 = fmaxf(v1, a2); v1 = a1; i1 = ai; }
      else { if (a1 == v1 && ai < i1) i1 = ai; v2 = fmaxf(v2, a1); }
    }
    idx_s[r] = i1;
    if (v1 - v2 < DELTA){ int p = atomicAdd(count, 1); if (p < 2*N_ROWS) list[p] = r | (1<<30); }
  }
}

// ---------------- f64 exact rescore of flagged rows ----------------
__global__ __launch_bounds__(256) void k_rescore(
    const float* __restrict__ x,
    const float* __restrict__ w_c, const float* __restrict__ w_s,
    const float* __restrict__ lnc_g, const float* __restrict__ lnc_b,
    const float* __restrict__ lns_g, const float* __restrict__ lns_b,
    const float* __restrict__ b_c, const float* __restrict__ b_s,
    const float* __restrict__ ccb, const float* __restrict__ scb,
    const int* __restrict__ list, const int* __restrict__ count,
    int* __restrict__ idx_c, int* __restrict__ idx_s){
  __shared__ double u[DM];
  __shared__ double f[HALF];
  __shared__ double redd[4];
  __shared__ double rvs[4]; __shared__ int ris[4];
  int n = *count; if (n > 2*N_ROWS) n = 2*N_ROWS; if (n < 0) n = 0;
  int t = threadIdx.x;
  for (int e = blockIdx.x; e < n; e += gridDim.x){
    int ent = list[e];
    int r = ent & 0x3FFFFFFF; int path = (ent >> 30) & 1;
    if (r >= N_ROWS) continue;
    const float* xr = x + (size_t)r*DM;
    double s = 0;
    for (int k=t; k<DM; k+=256) s += (double)xr[k];
    double mean = blockSumD(s, redd) * (1.0/1024.0);
    double s2 = 0;
    for (int k=t; k<DM; k+=256){ double d = (double)xr[k]-mean; s2 += d*d; }
    double var = blockSumD(s2, redd) * (1.0/1024.0);
    double rs = 1.0 / sqrt(var + 1e-5);
    const float* g  = path ? lns_g : lnc_g;
    const float* bl = path ? lns_b : lnc_b;
    for (int k=t; k<DM; k+=256)
      u[k] = ((double)xr[k]-mean)*rs*(double)g[k] + (double)bl[k];
    __syncthreads();
    const float* w  = path ? w_s : w_c;
    const float* bo = path ? b_s : b_c;
    for (int j=t; j<HALF; j+=256){
      double a0=0, a1=0;
      for (int k=0;k<DM;k+=2){
        a0 += u[k]  *(double)w[(size_t)k*HALF+j];
        a1 += u[k+1]*(double)w[(size_t)(k+1)*HALF+j];
      }
      f[j] = tanh(a0 + a1 + (double)bo[j]);
    }
    __syncthreads();
    const float* cb = path ? scb : ccb;
    int ncodes = path ? NS : NC;
    double bv = -1e300; int bi = 0;
    for (int c=t; c<ncodes; c+=256){
      const float4* cr = (const float4*)(cb + (size_t)c*HALF);
      double d0=0, d1=0, n0=0, n1=0;
      for (int k4=0;k4<128;k4+=2){
        float4 cv = cr[k4]; float4 cw = cr[k4+1];
        d0 += f[k4*4+0]*(double)cv.x + f[k4*4+1]*(double)cv.y + f[k4*4+2]*(double)cv.z + f[k4*4+3]*(double)cv.w;
        n0 += (double)cv.x*cv.x + (double)cv.y*cv.y + (double)cv.z*cv.z + (double)cv.w*cv.w;
        d1 += f[k4*4+4]*(double)cw.x + f[k4*4+5]*(double)cw.y + f[k4*4+6]*(double)cw.z + f[k4*4+7]*(double)cw.w;
        n1 += (double)cw.x*cw.x + (double)cw.y*cw.y + (double)cw.z*cw.z + (double)cw.w*cw.w;
      }
      double sim = (d0+d1) / fmax(sqrt(n0+n1), 1e-12);
      if (sim > bv || (sim == bv && c < bi)){ bv = sim; bi = c; }
    }
    #pragma unroll
    for (int m=1;m<64;m<<=1){
      double ov = __shfl_xor(bv, m, 64);
      int   oi = __shfl_xor(bi, m, 64);
      if (ov > bv || (ov == bv && oi < bi)){ bv = ov; bi = oi; }
    }
    __syncthreads();
    if ((t&63)==0){ rvs[t>>6]=bv; ris[t>>6]=bi; }
    __syncthreads();
    if (t==0){
      #pragma unroll
      for (int wv=1; wv<4; wv++)
        if (rvs[wv] > bv || (rvs[wv]==bv && ris[wv]<bi)){ bv=rvs[wv]; bi=ris[wv]; }
      if (path) idx_s[r] = bi; else idx_c[r] = bi;
    }
    __syncthreads();
  }
}

// ---------------- per-row losses (accumulators only) ----------------
__global__ __launch_bounds__(64) void k_loss(const float* __restrict__ feat,
    const float* __restrict__ cbn_c, const float* __restrict__ cbn_s,
    const int* __restrict__ idx_c, const int* __restrict__ idx_s,
    float* __restrict__ accum){
  int r = blockIdx.x, t = threadIdx.x;
  int ic = clampi(idx_c[r], NC-1), is_ = clampi(idx_s[r], NS-1);
  const float* cf = feat + (size_t)r*DM;
  const float* sf = cf + HALF;
  const float* qc = cbn_c + (size_t)ic*HALF;
  const float* qs = cbn_s + (size_t)is_*HALF;
  float ec=0, es=0, dt=0, nc2=0, ns2=0;
  #pragma unroll
  for (int i=0;i<2;i++){
    int o4 = t + i*64;
    float4 c4 = ((const float4*)cf)[o4];
    float4 s4 = ((const float4*)sf)[o4];
    float4 q4 = ((const float4*)qc)[o4];
    float4 p4 = ((const float4*)qs)[o4];
    float d;
    d=q4.x-c4.x; ec+=d*d; d=q4.y-c4.y; ec+=d*d; d=q4.z-c4.z; ec+=d*d; d=q4.w-c4.w; ec+=d*d;
    d=p4.x-s4.x; es+=d*d; d=p4.y-s4.y; es+=d*d; d=p4.z-s4.z; es+=d*d; d=p4.w-s4.w; es+=d*d;
    dt += c4.x*s4.x + c4.y*s4.y + c4.z*s4.z + c4.w*s4.w;
    nc2 += c4.x*c4.x + c4.y*c4.y + c4.z*c4.z + c4.w*c4.w;
    ns2 += s4.x*s4.x + s4.y*s4.y + s4.z*s4.z + s4.w*s4.w;
  }
  #pragma unroll
  for (int m=1;m<64;m<<=1){
    ec += __shfl_xor(ec, m, 64); es += __shfl_xor(es, m, 64);
    dt += __shfl_xor(dt, m, 64); nc2 += __shfl_xor(nc2, m, 64); ns2 += __shfl_xor(ns2, m, 64);
  }
  if (t == 0){
    float cosv = fabsf(dt) / (fmaxf(sqrtf(nc2),1e-12f)*fmaxf(sqrtf(ns2),1e-12f));
    atomicAdd(&accum[0], ec); atomicAdd(&accum[1], es); atomicAdd(&accum[2], cosv);
  }
}

// ---------------- combined GEMM (gathered quantized rows @ w_comb + b_comb) -> f32 staging ----------------
__global__ __launch_bounds__(256) void k_gemm_comb(
    const float* __restrict__ cbn_c, const float* __restrict__ cbn_s,
    const int* __restrict__ idx_c, const int* __restrict__ idx_s,
    const float* __restrict__ w_comb, const float* __restrict__ b_comb,
    float* __restrict__ combf){
  __shared__ __align__(16) float As[16][132];
  __shared__ __align__(16) float Bs[16][128];
  int row0 = blockIdx.x*128, col0 = blockIdx.y*128;
  int t = threadIdx.x;
  int tr = t & 15, tc = t >> 4;
  float acc[8][8];
  #pragma unroll
  for (int i=0;i<8;i++){
    #pragma unroll
    for (int j=0;j<8;j++) acc[i][j]=0.f;
  }
  for (int k0=0;k0<DM;k0+=16){
    #pragma unroll
    for (int i=0;i<2;i++){
      int s = t + i*256; int kq = s&3, rr = s>>2;
      int gr = row0 + rr;
      int kk = k0 + kq*4;
      const float* src;
      if (kk < HALF){ int ic = clampi(idx_c[gr], NC-1); src = cbn_c + (size_t)ic*HALF + kk; }
      else          { int is_ = clampi(idx_s[gr], NS-1); src = cbn_s + (size_t)is_*HALF + (kk-HALF); }
      float4 v = *(const float4*)src;
      As[kq*4+0][rr]=v.x; As[kq*4+1][rr]=v.y; As[kq*4+2][rr]=v.z; As[kq*4+3][rr]=v.w;
    }
    #pragma unroll
    for (int i=0;i<2;i++){
      int s = t + i*256; int jq = s&31, k = s>>5;
      float4 v = *(const float4*)(w_comb + (size_t)(k0+k)*DM + col0 + jq*4);
      *(float4*)&Bs[k][jq*4] = v;
    }
    __syncthreads();
    #pragma unroll
    for (int k=0;k<16;k++){
      float a[8], bb[8];
      *(float4*)&a[0] = *(const float4*)&As[k][tr*8];
      *(float4*)&a[4] = *(const float4*)&As[k][tr*8+4];
      *(float4*)&bb[0] = *(const float4*)&Bs[k][tc*8];
      *(float4*)&bb[4] = *(const float4*)&Bs[k][tc*8+4];
      #pragma unroll
      for (int i=0;i<8;i++)
        #pragma unroll
        for (int j=0;j<8;j++) acc[i][j] += a[i]*bb[j];
    }
    __syncthreads();
  }
  int gc0 = col0 + tc*8;
  #pragma unroll
  for (int i=0;i<8;i++){
    int gr = row0 + tr*8 + i;
    float o[8];
    #pragma unroll
    for (int j=0;j<8;j++) o[j] = acc[i][j] + b_comb[gc0+j];
    *(float4*)(combf + (size_t)gr*DM + gc0)     = *(float4*)&o[0];
    *(float4*)(combf + (size_t)gr*DM + gc0 + 4) = *(float4*)&o[4];
  }
}

// ---------------- LN over f32 staging -> f32 out (sole writer of chunk 0) ----------------
__global__ __launch_bounds__(256) void k_ln_out(const float* __restrict__ combf,
    const float* __restrict__ g, const float* __restrict__ b,
    float* __restrict__ out){
  __shared__ float red[4];
  int r = blockIdx.x, t = threadIdx.x;
  float4 v = ((const float4*)(combf + (size_t)r*DM))[t];
  float mean = blockSum256((v.x+v.y)+(v.z+v.w), red) * (1.0f/1024.0f);
  float dx=v.x-mean, dy=v.y-mean, dz=v.z-mean, dw=v.w-mean;
  float var = blockSum256((dx*dx+dy*dy)+(dz*dz+dw*dw), red) * (1.0f/1024.0f);
  float rs = 1.0f/sqrtf(var + 1e-5f);
  float4 gg = ((const float4*)g)[t];
  float4 bb = ((const float4*)b)[t];
  float4 o;
  o.x = dx*rs*gg.x + bb.x; o.y = dy*rs*gg.y + bb.y;
  o.z = dz*rs*gg.z + bb.z; o.w = dw*rs*gg.w + bb.w;
  ((float4*)out)[(size_t)r*256 + t] = o;
}

// ---------------- final: idx outputs + scalars (f32) ----------------
__global__ __launch_bounds__(256) void k_final(const int* __restrict__ idx_c, const int* __restrict__ idx_s,
                                               const float* __restrict__ accum, float* __restrict__ out){
  int r = blockIdx.x*256 + threadIdx.x;
  out[IDXC_OFF + r] = (float)idx_c[r];
  out[IDXS_OFF + r] = (float)idx_s[r];
  if (r == 0){
    float ec = accum[0] * (1.0f/((float)N_ROWS*(float)HALF));
    float es = accum[1] * (1.0f/((float)N_ROWS*(float)HALF));
    float cosm = accum[2] * (1.0f/(float)N_ROWS);
    float dis = fminf(fmaxf(cosm, 0.0f), 1.0f);
    float total = 0.1f*ec + 0.1f*es + 0.5f*dis;
    out[COMB_N]  = total;
    out[DIS_OFF] = dis;
  }
}

extern "C" void kernel_launch(void* const* d_in, const int* in_sizes, int n_in,
                              void* d_out, int out_size, void* d_ws, size_t ws_size,
                              hipStream_t stream){
  const float* x     = (const float*)d_in[0];
  const float* lnc_g = (const float*)d_in[1];
  const float* lnc_b = (const float*)d_in[2];
  const float* w_c   = (const float*)d_in[3];
  const float* b_c   = (const float*)d_in[4];
  const float* lns_g = (const float*)d_in[5];
  const float* lns_b = (const float*)d_in[6];
  const float* w_s   = (const float*)d_in[7];
  const float* b_s   = (const float*)d_in[8];
  const float* ccb   = (const float*)d_in[9];
  const float* scb   = (const float*)d_in[10];
  const float* w_cb  = (const float*)d_in[11];
  const float* b_cb  = (const float*)d_in[12];
  const float* lno_g = (const float*)d_in[13];
  const float* lno_b = (const float*)d_in[14];
  float* out = (float*)d_out;
  float* ws = (float*)d_ws;

  // small arrays first; feat (largest) last
  size_t o = 0;
  float* accum = ws + o; o += 16;
  int* count   = (int*)(ws + o); o += 16;
  float* mu    = ws + o; o += N_ROWS;
  float* rstd  = ws + o; o += N_ROWS;
  float* bias2 = ws + o; o += DM;
  int* idx_c   = (int*)(ws + o); o += N_ROWS;
  int* idx_s   = (int*)(ws + o); o += N_ROWS;
  int* list    = (int*)(ws + o); o += 2*N_ROWS;
  float* pcv1  = ws + o; o += 4*N_ROWS;
  int*   pci1  = (int*)(ws + o); o += 4*N_ROWS;
  float* pcv2  = ws + o; o += 4*N_ROWS;
  float* psv1  = ws + o; o += 4*N_ROWS;
  int*   psi1  = (int*)(ws + o); o += 4*N_ROWS;
  float* psv2  = ws + o; o += 4*N_ROWS;
  float* cbn_c = ws + o; o += (size_t)NC*HALF;
  float* cbn_s = ws + o; o += (size_t)NS*HALF;
  float* feat  = ws + o; o += (size_t)N_ROWS*DM;   // reused as combf after k_loss

  k_init<<<dim3(1), dim3(64), 0, stream>>>(accum, count);
  k_norm_cb<<<dim3(NC+NS), dim3(64), 0, stream>>>(ccb, scb, cbn_c, cbn_s);
  k_row_stats<<<dim3(N_ROWS), dim3(256), 0, stream>>>(x, mu, rstd);
  k_bias2<<<dim3(4), dim3(256), 0, stream>>>(w_c, w_s, lnc_b, lns_b, b_c, b_s, bias2);
  k_gemm_feat<<<dim3(128, 8), dim3(256), 0, stream>>>(x, mu, rstd, w_c, w_s, lnc_g, lns_g, bias2, feat);
  k_sims<<<dim3(256, 4), dim3(256), 0, stream>>>(feat, 0, cbn_c, NC, pcv1, pci1, pcv2);
  k_sims<<<dim3(256, 4), dim3(256), 0, stream>>>(feat, HALF, cbn_s, NS, psv1, psi1, psv2);
  k_argmax_merge<<<dim3(64), dim3(256), 0, stream>>>(pcv1, pci1, pcv2, psv1, psi1, psv2,
                                                     idx_c, idx_s, count, list);
  k_rescore<<<dim3(256), dim3(256), 0, stream>>>(x, w_c, w_s, lnc_g, lnc_b, lns_g, lns_b,
                                                 b_c, b_s, ccb, scb, list, count, idx_c, idx_s);
  k_loss<<<dim3(N_ROWS), dim3(64), 0, stream>>>(feat, cbn_c, cbn_s, idx_c, idx_s, accum);
  k_gemm_comb<<<dim3(128, 8), dim3(256), 0, stream>>>(cbn_c, cbn_s, idx_c, idx_s, w_cb, b_cb, feat);
  k_ln_out<<<dim3(N_ROWS), dim3(256), 0, stream>>>(feat, lno_g, lno_b, out);
  k_final<<<dim3(64), dim3(256), 0, stream>>>(idx_c, idx_s, accum, out);
}

// Round 5
// 2575.019 us; speedup vs baseline: 1.3135x; 1.3135x over previous
//
#include <hip/hip_runtime.h>
#include <hip/hip_bf16.h>
#include <math.h>

#define N_ROWS 16384      // 8*2048
#define DM 1024
#define HALF 512
#define NC 4096
#define NS 1024
#define DELTA 2e-3f       // unnormalized-sims gap threshold for f64 rescore

// f32-element offsets into d_out (chunks in reference return order)
#define COMB_N   16777216
#define IDXC_OFF 16777217
#define IDXS_OFF 16793601
#define DIS_OFF  16809985

typedef __attribute__((ext_vector_type(8))) short bf16x8;
typedef __attribute__((ext_vector_type(4))) float f32x4;

__device__ __forceinline__ int clampi(int v, int hi){ return v < 0 ? 0 : (v > hi ? hi : v); }

__device__ __forceinline__ unsigned short f2bu(float f){
  union { __hip_bfloat16 h; unsigned short u; } cv; cv.h = __float2bfloat16(f); return cv.u;
}
__device__ __forceinline__ float b2fu(unsigned short u){
  union { unsigned short u; __hip_bfloat16 h; } cv; cv.u = u; return __bfloat162float(cv.h);
}

__device__ __forceinline__ float blockSum256(float v, float* red){
  #pragma unroll
  for (int m=1;m<64;m<<=1) v += __shfl_xor(v, m, 64);
  __syncthreads();
  if ((threadIdx.x & 63) == 0) red[threadIdx.x>>6] = v;
  __syncthreads();
  return (red[0]+red[1])+(red[2]+red[3]);
}
__device__ __forceinline__ double blockSumD(double v, double* red){
  #pragma unroll
  for (int m=1;m<64;m<<=1) v += __shfl_xor(v, m, 64);
  __syncthreads();
  if ((threadIdx.x & 63) == 0) red[threadIdx.x>>6] = v;
  __syncthreads();
  return (red[0]+red[1])+(red[2]+red[3]);
}

// ---------------- init ----------------
__global__ void k_init(float* accum, int* count){
  if (threadIdx.x < 8) accum[threadIdx.x] = 0.f;
  if (threadIdx.x == 0) *count = 0;
}

// ---------------- normalize codebooks -> bf16 hi/lo split ----------------
__global__ __launch_bounds__(64) void k_norm_cb(const float* __restrict__ ccb, const float* __restrict__ scb,
                                                unsigned short* __restrict__ cbh_c, unsigned short* __restrict__ cbl_c,
                                                unsigned short* __restrict__ cbh_s, unsigned short* __restrict__ cbl_s){
  int b = blockIdx.x, t = threadIdx.x;
  const float* src; unsigned short *dh, *dl;
  if (b < NC){ src = ccb + (size_t)b*HALF; dh = cbh_c + (size_t)b*HALF; dl = cbl_c + (size_t)b*HALF; }
  else       { src = scb + (size_t)(b-NC)*HALF; dh = cbh_s + (size_t)(b-NC)*HALF; dl = cbl_s + (size_t)(b-NC)*HALF; }
  float4 a = ((const float4*)src)[t];
  float4 c = ((const float4*)src)[t+64];
  float s = a.x*a.x+a.y*a.y+a.z*a.z+a.w*a.w + c.x*c.x+c.y*c.y+c.z*c.z+c.w*c.w;
  #pragma unroll
  for (int m=1;m<64;m<<=1) s += __shfl_xor(s, m, 64);
  float inv = 1.0f / fmaxf(sqrtf(s), 1e-12f);
  float v[8] = {a.x*inv, a.y*inv, a.z*inv, a.w*inv, c.x*inv, c.y*inv, c.z*inv, c.w*inv};
  ushort4 h0, h1, l0, l1;
  unsigned short hv[8], lv[8];
  #pragma unroll
  for (int j=0;j<8;j++){ hv[j] = f2bu(v[j]); lv[j] = f2bu(v[j] - b2fu(hv[j])); }
  h0.x=hv[0]; h0.y=hv[1]; h0.z=hv[2]; h0.w=hv[3]; h1.x=hv[4]; h1.y=hv[5]; h1.z=hv[6]; h1.w=hv[7];
  l0.x=lv[0]; l0.y=lv[1]; l0.z=lv[2]; l0.w=lv[3]; l1.x=lv[4]; l1.y=lv[5]; l1.z=lv[6]; l1.w=lv[7];
  ((ushort4*)dh)[t] = h0; ((ushort4*)dh)[t+64] = h1;
  ((ushort4*)dl)[t] = l0; ((ushort4*)dl)[t+64] = l1;
}

// ---------------- per-row mean / rstd of x ----------------
__global__ __launch_bounds__(256) void k_row_stats(const float* __restrict__ x, float* __restrict__ mu, float* __restrict__ rstd){
  __shared__ float red[4];
  int r = blockIdx.x, t = threadIdx.x;
  float4 v = ((const float4*)(x + (size_t)r*DM))[t];
  float mean = blockSum256((v.x+v.y)+(v.z+v.w), red) * (1.0f/1024.0f);
  float dx=v.x-mean, dy=v.y-mean, dz=v.z-mean, dw=v.w-mean;
  float var = blockSum256((dx*dx+dy*dy)+(dz*dz+dw*dw), red) * (1.0f/1024.0f);
  if (t == 0){ mu[r] = mean; rstd[r] = 1.0f/sqrtf(var + 1e-5f); }
}

// ---------------- bias2[j] = b[j] + sum_k b_ln[k]*w[k][j] ----------------
__global__ __launch_bounds__(256) void k_bias2(const float* __restrict__ w_c, const float* __restrict__ w_s,
                                               const float* __restrict__ bc_ln, const float* __restrict__ bs_ln,
                                               const float* __restrict__ b_c, const float* __restrict__ b_s,
                                               float* __restrict__ bias2){
  int j = blockIdx.x*256 + threadIdx.x;
  float acc = 0.f;
  if (j < HALF){
    for (int k=0;k<DM;k++) acc += bc_ln[k]*w_c[(size_t)k*HALF + j];
    acc += b_c[j];
  } else {
    int jj = j - HALF;
    for (int k=0;k<DM;k++) acc += bs_ln[k]*w_s[(size_t)k*HALF + jj];
    acc += b_s[jj];
  }
  bias2[j] = acc;
}

// ---------------- features GEMM: feat = tanh(z @ (g.w) + bias2) -> bf16 hi/lo split ----------------
__global__ __launch_bounds__(256) void k_gemm_feat(const float* __restrict__ x,
    const float* __restrict__ mu, const float* __restrict__ rstd,
    const float* __restrict__ w_c, const float* __restrict__ w_s,
    const float* __restrict__ gc, const float* __restrict__ gs,
    const float* __restrict__ bias2,
    unsigned short* __restrict__ feat_hi, unsigned short* __restrict__ feat_lo){
  __shared__ __align__(16) float As[16][132];
  __shared__ __align__(16) float Bs[16][128];
  int row0 = blockIdx.x*128, col0 = blockIdx.y*128;
  const float* w = (col0 < HALF) ? w_c : w_s;
  const float* g = (col0 < HALF) ? gc  : gs;
  int wcol0 = (col0 < HALF) ? col0 : (col0 - HALF);
  int t = threadIdx.x;
  int tr = t & 15, tc = t >> 4;
  float acc[8][8];
  #pragma unroll
  for (int i=0;i<8;i++){
    #pragma unroll
    for (int j=0;j<8;j++) acc[i][j]=0.f;
  }
  for (int k0=0;k0<DM;k0+=16){
    #pragma unroll
    for (int i=0;i<2;i++){
      int s = t + i*256; int kq = s&3, rr = s>>2;
      int gr = row0 + rr;
      float4 v = *(const float4*)(x + (size_t)gr*DM + k0 + kq*4);
      float m = mu[gr], rs = rstd[gr];
      As[kq*4+0][rr]=(v.x-m)*rs; As[kq*4+1][rr]=(v.y-m)*rs;
      As[kq*4+2][rr]=(v.z-m)*rs; As[kq*4+3][rr]=(v.w-m)*rs;
    }
    #pragma unroll
    for (int i=0;i<2;i++){
      int s = t + i*256; int jq = s&31, k = s>>5;
      float gv = g[k0+k];
      float4 v = *(const float4*)(w + (size_t)(k0+k)*HALF + wcol0 + jq*4);
      Bs[k][jq*4+0] = gv*v.x; Bs[k][jq*4+1] = gv*v.y;
      Bs[k][jq*4+2] = gv*v.z; Bs[k][jq*4+3] = gv*v.w;
    }
    __syncthreads();
    #pragma unroll
    for (int k=0;k<16;k++){
      float a[8], bb[8];
      *(float4*)&a[0] = *(const float4*)&As[k][tr*8];
      *(float4*)&a[4] = *(const float4*)&As[k][tr*8+4];
      *(float4*)&bb[0] = *(const float4*)&Bs[k][tc*8];
      *(float4*)&bb[4] = *(const float4*)&Bs[k][tc*8+4];
      #pragma unroll
      for (int i=0;i<8;i++)
        #pragma unroll
        for (int j=0;j<8;j++) acc[i][j] += a[i]*bb[j];
    }
    __syncthreads();
  }
  int gc0 = col0 + tc*8;
  #pragma unroll
  for (int i=0;i<8;i++){
    int gr = row0 + tr*8 + i;
    unsigned short hv[8], lv[8];
    #pragma unroll
    for (int j=0;j<8;j++){
      float o = tanhf(acc[i][j] + bias2[gc0+j]);
      hv[j] = f2bu(o); lv[j] = f2bu(o - b2fu(hv[j]));
    }
    ushort4 h0{hv[0],hv[1],hv[2],hv[3]}, h1{hv[4],hv[5],hv[6],hv[7]};
    ushort4 l0{lv[0],lv[1],lv[2],lv[3]}, l1{lv[4],lv[5],lv[6],lv[7]};
    ushort4* ph = (ushort4*)(feat_hi + (size_t)gr*DM + gc0);
    ushort4* pl = (ushort4*)(feat_lo + (size_t)gr*DM + gc0);
    ph[0]=h0; ph[1]=h1; pl[0]=l0; pl[1]=l1;
  }
}

// ---------------- sims via split-bf16 MFMA + per-row running top2 ----------------
// block: 256 thr = 4 waves; wave w owns rows [row0+16w, +16); 128-code chunks.
__global__ __launch_bounds__(256) void k_sims(
    const unsigned short* __restrict__ feat_hi, const unsigned short* __restrict__ feat_lo, int featoff,
    const unsigned short* __restrict__ cb_hi, const unsigned short* __restrict__ cb_lo, int ncodes,
    float* __restrict__ pv1, int* __restrict__ pi1, float* __restrict__ pv2){
  __shared__ unsigned short Bh[128*64];   // [code][64k] bf16, byte ^= (code&7)<<4
  __shared__ unsigned short Bl[128*64];
  int row0 = blockIdx.x*64;
  int cchunk = ncodes >> 2;
  int c0base = blockIdx.y * cchunk;
  int t = threadIdx.x;
  int w = t >> 6, lane = t & 63;
  int ln = lane & 15, q = lane >> 4;
  const size_t abase = (size_t)(row0 + w*16 + ln)*DM + featoff + q*8;

  float rv1[4], rv2[4]; int ri1[4];
  #pragma unroll
  for (int g=0; g<4; g++){ rv1[g]=-1e30f; rv2[g]=-1e30f; ri1[g]=0; }

  for (int c0 = c0base; c0 < c0base + cchunk; c0 += 128){
    f32x4 acc[8];
    #pragma unroll
    for (int tl=0; tl<8; tl++) acc[tl] = (f32x4){0.f,0.f,0.f,0.f};
    for (int k0=0; k0<HALF; k0+=64){
      __syncthreads();
      #pragma unroll
      for (int i=0;i<4;i++){
        int u = t + i*256;
        int code = u >> 3, slot = u & 7;
        size_t gsrc = (size_t)(c0+code)*HALF + k0 + slot*8;
        int lb = (code*128 + slot*16) ^ ((code&7)<<4);
        *(bf16x8*)(&Bh[lb>>1]) = *(const bf16x8*)(cb_hi + gsrc);
        *(bf16x8*)(&Bl[lb>>1]) = *(const bf16x8*)(cb_lo + gsrc);
      }
      __syncthreads();
      #pragma unroll
      for (int ks=0; ks<2; ks++){
        size_t ak = abase + k0 + ks*32;
        bf16x8 ah = *(const bf16x8*)(feat_hi + ak);
        bf16x8 al = *(const bf16x8*)(feat_lo + ak);
        #pragma unroll
        for (int tl=0; tl<8; tl++){
          int code_l = tl*16 + ln;
          int lb = (code_l*128 + ks*64 + q*16) ^ ((ln&7)<<4);
          bf16x8 bh = *(const bf16x8*)(&Bh[lb>>1]);
          bf16x8 bl = *(const bf16x8*)(&Bl[lb>>1]);
          acc[tl] = __builtin_amdgcn_mfma_f32_16x16x32_bf16(ah, bh, acc[tl], 0, 0, 0);
          acc[tl] = __builtin_amdgcn_mfma_f32_16x16x32_bf16(ah, bl, acc[tl], 0, 0, 0);
          acc[tl] = __builtin_amdgcn_mfma_f32_16x16x32_bf16(al, bh, acc[tl], 0, 0, 0);
        }
      }
    }
    // local top2 update; value acc[tl][g] -> (row=q*4+g, code=c0+tl*16+ln)
    #pragma unroll
    for (int g=0; g<4; g++){
      float v1 = acc[0][g]; int i1 = c0 + ln; float v2 = -1e30f;
      #pragma unroll
      for (int tl=1; tl<8; tl++){
        float v = acc[tl][g];
        if (v > v1){ v2 = v1; v1 = v; i1 = c0 + tl*16 + ln; }
        else v2 = fmaxf(v2, v);
      }
      if (v1 > rv1[g]){ rv2[g] = fmaxf(rv1[g], v2); rv1[g] = v1; ri1[g] = i1; }
      else { if (v1 == rv1[g] && i1 < ri1[g]) ri1[g] = i1; rv2[g] = fmaxf(rv2[g], v1); }
    }
  }
  // butterfly merge across the 16 lanes of each quarter-wave
  int sbase = blockIdx.y * N_ROWS;
  #pragma unroll
  for (int g=0; g<4; g++){
    float v1 = rv1[g], v2 = rv2[g]; int i1 = ri1[g];
    #pragma unroll
    for (int m=1; m<16; m<<=1){
      float o1 = __shfl_xor(v1, m, 64);
      int   oi = __shfl_xor(i1, m, 64);
      float o2 = __shfl_xor(v2, m, 64);
      if (o1 > v1){ v2 = fmaxf(v1, o2); v1 = o1; i1 = oi; }
      else { if (o1 == v1 && oi < i1) i1 = oi; v2 = fmaxf(v2, o1); }
    }
    if (ln == 0){
      int r = row0 + w*16 + q*4 + g;
      pv1[sbase + r] = v1; pi1[sbase + r] = i1; pv2[sbase + r] = v2;
    }
  }
}

// ---------------- merge 4-way splits, flag close calls ----------------
__global__ __launch_bounds__(256) void k_argmax_merge(
    const float* __restrict__ pcv1, const int* __restrict__ pci1, const float* __restrict__ pcv2,
    const float* __restrict__ psv1, const int* __restrict__ psi1, const float* __restrict__ psv2,
    int* __restrict__ idx_c, int* __restrict__ idx_s,
    int* __restrict__ count, int* __restrict__ list){
  int r = blockIdx.x*256 + threadIdx.x;
  {
    float v1=-1e30f, v2=-1e30f; int i1=0;
    #pragma unroll
    for (int sp=0; sp<4; sp++){
      float a1 = pcv1[sp*N_ROWS + r]; int ai = pci1[sp*N_ROWS + r]; float a2 = pcv2[sp*N_ROWS + r];
      if (a1 > v1){ v2 = fmaxf(v1, a2); v1 = a1; i1 = ai; }
      else { if (a1 == v1 && ai < i1) i1 = ai; v2 = fmaxf(v2, a1); }
    }
    idx_c[r] = i1;
    if (v1 - v2 < DELTA){ int p = atomicAdd(count, 1); if (p < 2*N_ROWS) list[p] = r; }
  }
  {
    float v1=-1e30f, v2=-1e30f; int i1=0;
    #pragma unroll
    for (int sp=0; sp<4; sp++){
      float a1 = psv1[sp*N_ROWS + r]; int ai = psi1[sp*N_ROWS + r]; float a2 = psv2[sp*N_ROWS + r];
      if (a1 > v1){ v2 = fmaxf(v1, a2); v1 = a1; i1 = ai; }
      else { if (a1 == v1 && ai < i1) i1 = ai; v2 = fmaxf(v2, a1); }
    }
    idx_s[r] = i1;
    if (v1 - v2 < DELTA){ int p = atomicAdd(count, 1); if (p < 2*N_ROWS) list[p] = r | (1<<30); }
  }
}

// ---------------- f64 exact rescore of flagged rows ----------------
__global__ __launch_bounds__(256) void k_rescore(
    const float* __restrict__ x,
    const float* __restrict__ w_c, const float* __restrict__ w_s,
    const float* __restrict__ lnc_g, const float* __restrict__ lnc_b,
    const float* __restrict__ lns_g, const float* __restrict__ lns_b,
    const float* __restrict__ b_c, const float* __restrict__ b_s,
    const float* __restrict__ ccb, const float* __restrict__ scb,
    const int* __restrict__ list, const int* __restrict__ count,
    int* __restrict__ idx_c, int* __restrict__ idx_s){
  __shared__ double u[DM];
  __shared__ double f[HALF];
  __shared__ double redd[4];
  __shared__ double rvs[4]; __shared__ int ris[4];
  int n = *count; if (n > 2*N_ROWS) n = 2*N_ROWS; if (n < 0) n = 0;
  int t = threadIdx.x;
  for (int e = blockIdx.x; e < n; e += gridDim.x){
    int ent = list[e];
    int r = ent & 0x3FFFFFFF; int path = (ent >> 30) & 1;
    if (r >= N_ROWS) continue;
    const float* xr = x + (size_t)r*DM;
    double s = 0;
    for (int k=t; k<DM; k+=256) s += (double)xr[k];
    double mean = blockSumD(s, redd) * (1.0/1024.0);
    double s2 = 0;
    for (int k=t; k<DM; k+=256){ double d = (double)xr[k]-mean; s2 += d*d; }
    double var = blockSumD(s2, redd) * (1.0/1024.0);
    double rs = 1.0 / sqrt(var + 1e-5);
    const float* g  = path ? lns_g : lnc_g;
    const float* bl = path ? lns_b : lnc_b;
    for (int k=t; k<DM; k+=256)
      u[k] = ((double)xr[k]-mean)*rs*(double)g[k] + (double)bl[k];
    __syncthreads();
    const float* w  = path ? w_s : w_c;
    const float* bo = path ? b_s : b_c;
    for (int j=t; j<HALF; j+=256){
      double a0=0, a1=0;
      for (int k=0;k<DM;k+=2){
        a0 += u[k]  *(double)w[(size_t)k*HALF+j];
        a1 += u[k+1]*(double)w[(size_t)(k+1)*HALF+j];
      }
      f[j] = tanh(a0 + a1 + (double)bo[j]);
    }
    __syncthreads();
    const float* cb = path ? scb : ccb;
    int ncodes = path ? NS : NC;
    double bv = -1e300; int bi = 0;
    for (int c=t; c<ncodes; c+=256){
      const float4* cr = (const float4*)(cb + (size_t)c*HALF);
      double d0=0, d1=0, n0=0, n1=0;
      for (int k4=0;k4<128;k4+=2){
        float4 cv = cr[k4]; float4 cw = cr[k4+1];
        d0 += f[k4*4+0]*(double)cv.x + f[k4*4+1]*(double)cv.y + f[k4*4+2]*(double)cv.z + f[k4*4+3]*(double)cv.w;
        n0 += (double)cv.x*cv.x + (double)cv.y*cv.y + (double)cv.z*cv.z + (double)cv.w*cv.w;
        d1 += f[k4*4+4]*(double)cw.x + f[k4*4+5]*(double)cw.y + f[k4*4+6]*(double)cw.z + f[k4*4+7]*(double)cw.w;
        n1 += (double)cw.x*cw.x + (double)cw.y*cw.y + (double)cw.z*cw.z + (double)cw.w*cw.w;
      }
      double sim = (d0+d1) / fmax(sqrt(n0+n1), 1e-12);
      if (sim > bv || (sim == bv && c < bi)){ bv = sim; bi = c; }
    }
    #pragma unroll
    for (int m=1;m<64;m<<=1){
      double ov = __shfl_xor(bv, m, 64);
      int   oi = __shfl_xor(bi, m, 64);
      if (ov > bv || (ov == bv && oi < bi)){ bv = ov; bi = oi; }
    }
    __syncthreads();
    if ((t&63)==0){ rvs[t>>6]=bv; ris[t>>6]=bi; }
    __syncthreads();
    if (t==0){
      #pragma unroll
      for (int wv=1; wv<4; wv++)
        if (rvs[wv] > bv || (rvs[wv]==bv && ris[wv]<bi)){ bv=rvs[wv]; bi=ris[wv]; }
      if (path) idx_s[r] = bi; else idx_c[r] = bi;
    }
    __syncthreads();
  }
}

// ---------------- per-row losses (hi/lo reconstruction) ----------------
__global__ __launch_bounds__(64) void k_loss(
    const unsigned short* __restrict__ feat_hi, const unsigned short* __restrict__ feat_lo,
    const unsigned short* __restrict__ cbh_c, const unsigned short* __restrict__ cbl_c,
    const unsigned short* __restrict__ cbh_s, const unsigned short* __restrict__ cbl_s,
    const int* __restrict__ idx_c, const int* __restrict__ idx_s,
    float* __restrict__ accum){
  int r = blockIdx.x, t = threadIdx.x;
  int ic = clampi(idx_c[r], NC-1), is_ = clampi(idx_s[r], NS-1);
  const unsigned short* cfh = feat_hi + (size_t)r*DM;
  const unsigned short* cfl = feat_lo + (size_t)r*DM;
  float ec=0, es=0, dt=0, nc2=0, ns2=0;
  #pragma unroll
  for (int i=0;i<2;i++){
    int o4 = t + i*64;   // float4-unit index within 512
    ushort4 ch = ((const ushort4*)cfh)[o4];          ushort4 cl = ((const ushort4*)cfl)[o4];
    ushort4 sh = ((const ushort4*)(cfh+HALF))[o4];   ushort4 sl = ((const ushort4*)(cfl+HALF))[o4];
    ushort4 qh = ((const ushort4*)(cbh_c + (size_t)ic*HALF))[o4];
    ushort4 ql = ((const ushort4*)(cbl_c + (size_t)ic*HALF))[o4];
    ushort4 ph = ((const ushort4*)(cbh_s + (size_t)is_*HALF))[o4];
    ushort4 pl = ((const ushort4*)(cbl_s + (size_t)is_*HALF))[o4];
    float c4[4] = {b2fu(ch.x)+b2fu(cl.x), b2fu(ch.y)+b2fu(cl.y), b2fu(ch.z)+b2fu(cl.z), b2fu(ch.w)+b2fu(cl.w)};
    float s4[4] = {b2fu(sh.x)+b2fu(sl.x), b2fu(sh.y)+b2fu(sl.y), b2fu(sh.z)+b2fu(sl.z), b2fu(sh.w)+b2fu(sl.w)};
    float q4[4] = {b2fu(qh.x)+b2fu(ql.x), b2fu(qh.y)+b2fu(ql.y), b2fu(qh.z)+b2fu(ql.z), b2fu(qh.w)+b2fu(ql.w)};
    float p4[4] = {b2fu(ph.x)+b2fu(pl.x), b2fu(ph.y)+b2fu(pl.y), b2fu(ph.z)+b2fu(pl.z), b2fu(ph.w)+b2fu(pl.w)};
    #pragma unroll
    for (int j=0;j<4;j++){
      float d1 = q4[j]-c4[j]; ec += d1*d1;
      float d2 = p4[j]-s4[j]; es += d2*d2;
      dt += c4[j]*s4[j]; nc2 += c4[j]*c4[j]; ns2 += s4[j]*s4[j];
    }
  }
  #pragma unroll
  for (int m=1;m<64;m<<=1){
    ec += __shfl_xor(ec, m, 64); es += __shfl_xor(es, m, 64);
    dt += __shfl_xor(dt, m, 64); nc2 += __shfl_xor(nc2, m, 64); ns2 += __shfl_xor(ns2, m, 64);
  }
  if (t == 0){
    float cosv = fabsf(dt) / (fmaxf(sqrtf(nc2),1e-12f)*fmaxf(sqrtf(ns2),1e-12f));
    atomicAdd(&accum[0], ec); atomicAdd(&accum[1], es); atomicAdd(&accum[2], cosv);
  }
}

// ---------------- combined GEMM (gather hi+lo reconstructed) -> f32 staging ----------------
__global__ __launch_bounds__(256) void k_gemm_comb(
    const unsigned short* __restrict__ cbh_c, const unsigned short* __restrict__ cbl_c,
    const unsigned short* __restrict__ cbh_s, const unsigned short* __restrict__ cbl_s,
    const int* __restrict__ idx_c, const int* __restrict__ idx_s,
    const float* __restrict__ w_comb, const float* __restrict__ b_comb,
    float* __restrict__ combf){
  __shared__ __align__(16) float As[16][132];
  __shared__ __align__(16) float Bs[16][128];
  int row0 = blockIdx.x*128, col0 = blockIdx.y*128;
  int t = threadIdx.x;
  int tr = t & 15, tc = t >> 4;
  float acc[8][8];
  #pragma unroll
  for (int i=0;i<8;i++){
    #pragma unroll
    for (int j=0;j<8;j++) acc[i][j]=0.f;
  }
  for (int k0=0;k0<DM;k0+=16){
    #pragma unroll
    for (int i=0;i<2;i++){
      int s = t + i*256; int kq = s&3, rr = s>>2;
      int gr = row0 + rr;
      int kk = k0 + kq*4;
      const unsigned short *sh, *sl;
      if (kk < HALF){ int ic = clampi(idx_c[gr], NC-1); sh = cbh_c + (size_t)ic*HALF + kk; sl = cbl_c + (size_t)ic*HALF + kk; }
      else          { int is_ = clampi(idx_s[gr], NS-1); sh = cbh_s + (size_t)is_*HALF + (kk-HALF); sl = cbl_s + (size_t)is_*HALF + (kk-HALF); }
      ushort4 h = *(const ushort4*)sh; ushort4 l = *(const ushort4*)sl;
      As[kq*4+0][rr]=b2fu(h.x)+b2fu(l.x); As[kq*4+1][rr]=b2fu(h.y)+b2fu(l.y);
      As[kq*4+2][rr]=b2fu(h.z)+b2fu(l.z); As[kq*4+3][rr]=b2fu(h.w)+b2fu(l.w);
    }
    #pragma unroll
    for (int i=0;i<2;i++){
      int s = t + i*256; int jq = s&31, k = s>>5;
      float4 v = *(const float4*)(w_comb + (size_t)(k0+k)*DM + col0 + jq*4);
      *(float4*)&Bs[k][jq*4] = v;
    }
    __syncthreads();
    #pragma unroll
    for (int k=0;k<16;k++){
      float a[8], bb[8];
      *(float4*)&a[0] = *(const float4*)&As[k][tr*8];
      *(float4*)&a[4] = *(const float4*)&As[k][tr*8+4];
      *(float4*)&bb[0] = *(const float4*)&Bs[k][tc*8];
      *(float4*)&bb[4] = *(const float4*)&Bs[k][tc*8+4];
      #pragma unroll
      for (int i=0;i<8;i++)
        #pragma unroll
        for (int j=0;j<8;j++) acc[i][j] += a[i]*bb[j];
    }
    __syncthreads();
  }
  int gc0 = col0 + tc*8;
  #pragma unroll
  for (int i=0;i<8;i++){
    int gr = row0 + tr*8 + i;
    float o[8];
    #pragma unroll
    for (int j=0;j<8;j++) o[j] = acc[i][j] + b_comb[gc0+j];
    *(float4*)(combf + (size_t)gr*DM + gc0)     = *(float4*)&o[0];
    *(float4*)(combf + (size_t)gr*DM + gc0 + 4) = *(float4*)&o[4];
  }
}

// ---------------- LN over f32 staging -> f32 out (sole writer of chunk 0) ----------------
__global__ __launch_bounds__(256) void k_ln_out(const float* __restrict__ combf,
    const float* __restrict__ g, const float* __restrict__ b,
    float* __restrict__ out){
  __shared__ float red[4];
  int r = blockIdx.x, t = threadIdx.x;
  float4 v = ((const float4*)(combf + (size_t)r*DM))[t];
  float mean = blockSum256((v.x+v.y)+(v.z+v.w), red) * (1.0f/1024.0f);
  float dx=v.x-mean, dy=v.y-mean, dz=v.z-mean, dw=v.w-mean;
  float var = blockSum256((dx*dx+dy*dy)+(dz*dz+dw*dw), red) * (1.0f/1024.0f);
  float rs = 1.0f/sqrtf(var + 1e-5f);
  float4 gg = ((const float4*)g)[t];
  float4 bb = ((const float4*)b)[t];
  float4 o;
  o.x = dx*rs*gg.x + bb.x; o.y = dy*rs*gg.y + bb.y;
  o.z = dz*rs*gg.z + bb.z; o.w = dw*rs*gg.w + bb.w;
  ((float4*)out)[(size_t)r*256 + t] = o;
}

// ---------------- final: idx outputs + scalars (f32) ----------------
__global__ __launch_bounds__(256) void k_final(const int* __restrict__ idx_c, const int* __restrict__ idx_s,
                                               const float* __restrict__ accum, float* __restrict__ out){
  int r = blockIdx.x*256 + threadIdx.x;
  out[IDXC_OFF + r] = (float)idx_c[r];
  out[IDXS_OFF + r] = (float)idx_s[r];
  if (r == 0){
    float ec = accum[0] * (1.0f/((float)N_ROWS*(float)HALF));
    float es = accum[1] * (1.0f/((float)N_ROWS*(float)HALF));
    float cosm = accum[2] * (1.0f/(float)N_ROWS);
    float dis = fminf(fmaxf(cosm, 0.0f), 1.0f);
    float total = 0.1f*ec + 0.1f*es + 0.5f*dis;
    out[COMB_N]  = total;
    out[DIS_OFF] = dis;
  }
}

extern "C" void kernel_launch(void* const* d_in, const int* in_sizes, int n_in,
                              void* d_out, int out_size, void* d_ws, size_t ws_size,
                              hipStream_t stream){
  const float* x     = (const float*)d_in[0];
  const float* lnc_g = (const float*)d_in[1];
  const float* lnc_b = (const float*)d_in[2];
  const float* w_c   = (const float*)d_in[3];
  const float* b_c   = (const float*)d_in[4];
  const float* lns_g = (const float*)d_in[5];
  const float* lns_b = (const float*)d_in[6];
  const float* w_s   = (const float*)d_in[7];
  const float* b_s   = (const float*)d_in[8];
  const float* ccb   = (const float*)d_in[9];
  const float* scb   = (const float*)d_in[10];
  const float* w_cb  = (const float*)d_in[11];
  const float* b_cb  = (const float*)d_in[12];
  const float* lno_g = (const float*)d_in[13];
  const float* lno_b = (const float*)d_in[14];
  float* out = (float*)d_out;
  char* wsb = (char*)d_ws;

  size_t o = 0;
  auto alloc = [&](size_t bytes)->char*{ char* p = wsb + o; o += (bytes + 255) & ~(size_t)255; return p; };
  float* accum = (float*)alloc(64);
  int*   count = (int*)alloc(64);
  float* mu    = (float*)alloc(N_ROWS*4);
  float* rstd  = (float*)alloc(N_ROWS*4);
  float* bias2 = (float*)alloc(DM*4);
  int* idx_c   = (int*)alloc(N_ROWS*4);
  int* idx_s   = (int*)alloc(N_ROWS*4);
  int* list    = (int*)alloc(2*N_ROWS*4);
  float* pcv1  = (float*)alloc(4*N_ROWS*4);
  int*   pci1  = (int*)alloc(4*N_ROWS*4);
  float* pcv2  = (float*)alloc(4*N_ROWS*4);
  float* psv1  = (float*)alloc(4*N_ROWS*4);
  int*   psi1  = (int*)alloc(4*N_ROWS*4);
  float* psv2  = (float*)alloc(4*N_ROWS*4);
  unsigned short* cbh_c = (unsigned short*)alloc((size_t)NC*HALF*2);
  unsigned short* cbl_c = (unsigned short*)alloc((size_t)NC*HALF*2);
  unsigned short* cbh_s = (unsigned short*)alloc((size_t)NS*HALF*2);
  unsigned short* cbl_s = (unsigned short*)alloc((size_t)NS*HALF*2);
  unsigned short* feat_hi = (unsigned short*)alloc((size_t)N_ROWS*DM*2);
  unsigned short* feat_lo = (unsigned short*)alloc((size_t)N_ROWS*DM*2);
  float* combf = (float*)feat_hi;   // 64MB reuse: spans feat_hi+feat_lo after k_loss

  k_init<<<dim3(1), dim3(64), 0, stream>>>(accum, count);
  k_norm_cb<<<dim3(NC+NS), dim3(64), 0, stream>>>(ccb, scb, cbh_c, cbl_c, cbh_s, cbl_s);
  k_row_stats<<<dim3(N_ROWS), dim3(256), 0, stream>>>(x, mu, rstd);
  k_bias2<<<dim3(4), dim3(256), 0, stream>>>(w_c, w_s, lnc_b, lns_b, b_c, b_s, bias2);
  k_gemm_feat<<<dim3(128, 8), dim3(256), 0, stream>>>(x, mu, rstd, w_c, w_s, lnc_g, lns_g, bias2, feat_hi, feat_lo);
  k_sims<<<dim3(256, 4), dim3(256), 0, stream>>>(feat_hi, feat_lo, 0,    cbh_c, cbl_c, NC, pcv1, pci1, pcv2);
  k_sims<<<dim3(256, 4), dim3(256), 0, stream>>>(feat_hi, feat_lo, HALF, cbh_s, cbl_s, NS, psv1, psi1, psv2);
  k_argmax_merge<<<dim3(64), dim3(256), 0, stream>>>(pcv1, pci1, pcv2, psv1, psi1, psv2,
                                                     idx_c, idx_s, count, list);
  k_rescore<<<dim3(256), dim3(256), 0, stream>>>(x, w_c, w_s, lnc_g, lnc_b, lns_g, lns_b,
                                                 b_c, b_s, ccb, scb, list, count, idx_c, idx_s);
  k_loss<<<dim3(N_ROWS), dim3(64), 0, stream>>>(feat_hi, feat_lo, cbh_c, cbl_c, cbh_s, cbl_s, idx_c, idx_s, accum);
  k_gemm_comb<<<dim3(128, 8), dim3(256), 0, stream>>>(cbh_c, cbl_c, cbh_s, cbl_s, idx_c, idx_s, w_cb, b_cb, combf);
  k_ln_out<<<dim3(N_ROWS), dim3(256), 0, stream>>>(combf, lno_g, lno_b, out);
  k_final<<<dim3(64), dim3(256), 0, stream>>>(idx_c, idx_s, accum, out);
}